// Round 1
// baseline (5133.323 us; speedup 1.0000x reference)
//
#include <hip/hip_runtime.h>
#include <math.h>

#define B_DIM 512
#define WS_DIM 128
#define I_DIM 256
#define H_DIM 512
#define NWS 64
#define PRE 24

// ---------------------------------------------------------------------------
// K1: fc1 over the time axis.
// y[b,n,i] = sum_t x[b,t,i] * fc1_w[n,t] + fc1_b[n]
// grid: (NWS/8, B), block: 256 threads (one i per thread).
// Each block computes 8 consecutive n for one b; x reads coalesced over i.
// ---------------------------------------------------------------------------
__global__ void fc1_kernel(const float* __restrict__ x,
                           const float* __restrict__ fc1_w,
                           const float* __restrict__ fc1_b,
                           float* __restrict__ y) {
    __shared__ float w8[8][WS_DIM];
    const int b = blockIdx.y;
    const int n0 = blockIdx.x * 8;
    const int tid = threadIdx.x;

    for (int idx = tid; idx < 8 * WS_DIM; idx += 256) {
        w8[idx / WS_DIM][idx % WS_DIM] = fc1_w[(size_t)(n0 + idx / WS_DIM) * WS_DIM + (idx % WS_DIM)];
    }
    __syncthreads();

    const int i = tid;  // blockDim.x == I_DIM == 256
    float acc[8];
#pragma unroll
    for (int k = 0; k < 8; ++k) acc[k] = fc1_b[n0 + k];

    const float* xb = x + (size_t)b * WS_DIM * I_DIM + i;
    for (int t = 0; t < WS_DIM; ++t) {
        float xv = xb[(size_t)t * I_DIM];
#pragma unroll
        for (int k = 0; k < 8; ++k) acc[k] += xv * w8[k][t];
    }

    float* yb = y + ((size_t)b * NWS + n0) * I_DIM + i;
#pragma unroll
    for (int k = 0; k < 8; ++k) yb[(size_t)k * I_DIM] = acc[k];
}

// ---------------------------------------------------------------------------
// K2: fused GRU step.
// For each (b, j) computes:
//   a_r  = y[b,step,:].W_ih[j,:]      + h[b,:].W_hh[j,:]      + b_ih[j]+b_hh[j]
//   a_z  = same with rows H+j
//   gx_n = y[b,step,:].W_ih[2H+j,:]   + b_ih[2H+j]
//   gh_n = h[b,:].W_hh[2H+j,:]        + b_hh[2H+j]
//   r=sig(a_r) z=sig(a_z) n=tanh(gx_n + r*gh_n)
//   h_new = (1-z)*n + z*h
// grid: (H/32, B/32) = (16,16), block: 16x16 threads, 2x2 microtile/thread.
// ---------------------------------------------------------------------------
__global__ void gru_step_kernel(const float* __restrict__ y,     // [B,NWS,I]
                                const float* __restrict__ Wih,   // [3H, I]
                                const float* __restrict__ bih,   // [3H]
                                const float* __restrict__ Whh,   // [3H, H]
                                const float* __restrict__ bhh,   // [3H]
                                const float* __restrict__ h_in,  // [B,H]
                                float* __restrict__ h_out,       // [B,H]
                                float* __restrict__ h_seq,       // [B,PRE,H] or null
                                int step) {
    __shared__ float At[32][33];
    __shared__ float Wr[32][33];
    __shared__ float Wz[32][33];
    __shared__ float Wn[32][33];

    const int tx = threadIdx.x;  // 0..15 -> hidden cols
    const int ty = threadIdx.y;  // 0..15 -> batch rows
    const int tid = ty * 16 + tx;
    const int brow = blockIdx.y * 32;  // batch base
    const int bcol = blockIdx.x * 32;  // hidden-j base

    float accr[2][2], accz[2][2], accnx[2][2], accnh[2][2];
#pragma unroll
    for (int a = 0; a < 2; ++a) {
#pragma unroll
        for (int c = 0; c < 2; ++c) {
            int j = bcol + 2 * tx + c;
            accr[a][c]  = bih[j] + bhh[j];
            accz[a][c]  = bih[H_DIM + j] + bhh[H_DIM + j];
            accnx[a][c] = bih[2 * H_DIM + j];
            accnh[a][c] = bhh[2 * H_DIM + j];
        }
    }

    // ---- Phase A: input-side, K = I_DIM over y[b, step, :] ----
    for (int k0 = 0; k0 < I_DIM; k0 += 32) {
        for (int idx = tid; idx < 32 * 32; idx += 256) {
            int r = idx / 32, k = idx % 32;
            At[r][k] = y[(((size_t)(brow + r)) * NWS + step) * I_DIM + k0 + k];
            Wr[r][k] = Wih[(size_t)(bcol + r) * I_DIM + k0 + k];
            Wz[r][k] = Wih[(size_t)(H_DIM + bcol + r) * I_DIM + k0 + k];
            Wn[r][k] = Wih[(size_t)(2 * H_DIM + bcol + r) * I_DIM + k0 + k];
        }
        __syncthreads();
#pragma unroll
        for (int k = 0; k < 32; ++k) {
            float av[2] = {At[2 * ty][k], At[2 * ty + 1][k]};
            float wr[2] = {Wr[2 * tx][k], Wr[2 * tx + 1][k]};
            float wz[2] = {Wz[2 * tx][k], Wz[2 * tx + 1][k]};
            float wn[2] = {Wn[2 * tx][k], Wn[2 * tx + 1][k]};
#pragma unroll
            for (int a = 0; a < 2; ++a) {
#pragma unroll
                for (int c = 0; c < 2; ++c) {
                    accr[a][c]  += av[a] * wr[c];
                    accz[a][c]  += av[a] * wz[c];
                    accnx[a][c] += av[a] * wn[c];
                }
            }
        }
        __syncthreads();
    }

    // ---- Phase B: hidden-side, K = H_DIM over h_in[b, :] ----
    for (int k0 = 0; k0 < H_DIM; k0 += 32) {
        for (int idx = tid; idx < 32 * 32; idx += 256) {
            int r = idx / 32, k = idx % 32;
            At[r][k] = h_in[(size_t)(brow + r) * H_DIM + k0 + k];
            Wr[r][k] = Whh[(size_t)(bcol + r) * H_DIM + k0 + k];
            Wz[r][k] = Whh[(size_t)(H_DIM + bcol + r) * H_DIM + k0 + k];
            Wn[r][k] = Whh[(size_t)(2 * H_DIM + bcol + r) * H_DIM + k0 + k];
        }
        __syncthreads();
#pragma unroll
        for (int k = 0; k < 32; ++k) {
            float av[2] = {At[2 * ty][k], At[2 * ty + 1][k]};
            float wr[2] = {Wr[2 * tx][k], Wr[2 * tx + 1][k]};
            float wz[2] = {Wz[2 * tx][k], Wz[2 * tx + 1][k]};
            float wn[2] = {Wn[2 * tx][k], Wn[2 * tx + 1][k]};
#pragma unroll
            for (int a = 0; a < 2; ++a) {
#pragma unroll
                for (int c = 0; c < 2; ++c) {
                    accr[a][c]  += av[a] * wr[c];
                    accz[a][c]  += av[a] * wz[c];
                    accnh[a][c] += av[a] * wn[c];
                }
            }
        }
        __syncthreads();
    }

    // ---- Epilogue: gating ----
#pragma unroll
    for (int a = 0; a < 2; ++a) {
        int bb = brow + 2 * ty + a;
#pragma unroll
        for (int c = 0; c < 2; ++c) {
            int j = bcol + 2 * tx + c;
            float r = 1.0f / (1.0f + expf(-accr[a][c]));
            float z = 1.0f / (1.0f + expf(-accz[a][c]));
            float n = tanhf(accnx[a][c] + r * accnh[a][c]);
            float hprev = h_in[(size_t)bb * H_DIM + j];
            float hnew = (1.0f - z) * n + z * hprev;
            h_out[(size_t)bb * H_DIM + j] = hnew;
            if (h_seq) {
                h_seq[((size_t)bb * PRE + (step - (NWS - PRE))) * H_DIM + j] = hnew;
            }
        }
    }
}

// ---------------------------------------------------------------------------
// K3: fc2. out[b,tt,o] = sum_h hseq[b,tt,h]*fc2_w[o,h] + fc2_b[o]
// Treated as GEMM [B*PRE, H] x [I, H]^T.
// grid: (I/32, B*PRE/32) = (8, 384), block 16x16, 2x2 microtile.
// ---------------------------------------------------------------------------
__global__ void fc2_kernel(const float* __restrict__ hseq,  // [B*PRE, H]
                           const float* __restrict__ w,     // [I, H]
                           const float* __restrict__ bias,  // [I]
                           float* __restrict__ out) {       // [B*PRE, I]
    __shared__ float At[32][33];
    __shared__ float Bt[32][33];

    const int tx = threadIdx.x;
    const int ty = threadIdx.y;
    const int tid = ty * 16 + tx;
    const int brow = blockIdx.y * 32;  // over B*PRE
    const int bcol = blockIdx.x * 32;  // over I

    float acc[2][2];
#pragma unroll
    for (int a = 0; a < 2; ++a)
#pragma unroll
        for (int c = 0; c < 2; ++c) acc[a][c] = bias[bcol + 2 * tx + c];

    for (int k0 = 0; k0 < H_DIM; k0 += 32) {
        for (int idx = tid; idx < 32 * 32; idx += 256) {
            int r = idx / 32, k = idx % 32;
            At[r][k] = hseq[(size_t)(brow + r) * H_DIM + k0 + k];
            Bt[r][k] = w[(size_t)(bcol + r) * H_DIM + k0 + k];
        }
        __syncthreads();
#pragma unroll
        for (int k = 0; k < 32; ++k) {
            float av[2] = {At[2 * ty][k], At[2 * ty + 1][k]};
            float bv[2] = {Bt[2 * tx][k], Bt[2 * tx + 1][k]};
#pragma unroll
            for (int a = 0; a < 2; ++a)
#pragma unroll
                for (int c = 0; c < 2; ++c) acc[a][c] += av[a] * bv[c];
        }
        __syncthreads();
    }

#pragma unroll
    for (int a = 0; a < 2; ++a) {
        int rr = brow + 2 * ty + a;
#pragma unroll
        for (int c = 0; c < 2; ++c) {
            out[(size_t)rr * I_DIM + bcol + 2 * tx + c] = acc[a][c];
        }
    }
}

extern "C" void kernel_launch(void* const* d_in, const int* in_sizes, int n_in,
                              void* d_out, int out_size, void* d_ws, size_t ws_size,
                              hipStream_t stream) {
    const float* x     = (const float*)d_in[0];
    const float* fc1_w = (const float*)d_in[1];
    const float* fc1_b = (const float*)d_in[2];
    const float* W_ih  = (const float*)d_in[3];
    const float* W_hh  = (const float*)d_in[4];
    const float* b_ih  = (const float*)d_in[5];
    const float* b_hh  = (const float*)d_in[6];
    const float* fc2_w = (const float*)d_in[7];
    const float* fc2_b = (const float*)d_in[8];
    float* out = (float*)d_out;

    float* ws = (float*)d_ws;
    float* y    = ws;                                   // B*NWS*I  = 8388608
    float* h0   = y  + (size_t)B_DIM * NWS * I_DIM;     // B*H      = 262144
    float* h1   = h0 + (size_t)B_DIM * H_DIM;           // B*H      = 262144
    float* hseq = h1 + (size_t)B_DIM * H_DIM;           // B*PRE*H  = 6291456

    hipMemsetAsync(h0, 0, (size_t)B_DIM * H_DIM * sizeof(float), stream);

    fc1_kernel<<<dim3(NWS / 8, B_DIM), dim3(256), 0, stream>>>(x, fc1_w, fc1_b, y);

    dim3 blk2(16, 16);
    float* hin = h0;
    float* hout = h1;
    for (int step = 0; step < NWS; ++step) {
        float* hs = (step >= NWS - PRE) ? hseq : nullptr;
        gru_step_kernel<<<dim3(H_DIM / 32, B_DIM / 32), blk2, 0, stream>>>(
            y, W_ih, b_ih, W_hh, b_hh, hin, hout, hs, step);
        float* t = hin; hin = hout; hout = t;
    }

    fc2_kernel<<<dim3(I_DIM / 32, (B_DIM * PRE) / 32), blk2, 0, stream>>>(
        hseq, fc2_w, fc2_b, out);
}

// Round 2
// 3743.476 us; speedup vs baseline: 1.3713x; 1.3713x over previous
//
#include <hip/hip_runtime.h>
#include <hip/hip_cooperative_groups.h>
#include <math.h>

namespace cg = cooperative_groups;

#define B_DIM 512
#define WS_DIM 128
#define I_DIM 256
#define H_DIM 512
#define NWS 64
#define PRE 24
#define SEQ0 (NWS - PRE)  // 40

typedef __attribute__((ext_vector_type(8))) short short8;
typedef __attribute__((ext_vector_type(4))) float f32x4;

#define MFMA16(a, b, c) __builtin_amdgcn_mfma_f32_16x16x32_bf16((a), (b), (c), 0, 0, 0)

__device__ __forceinline__ unsigned short f2bf(float f) {
    unsigned u = __float_as_uint(f);
    u += 0x7FFF + ((u >> 16) & 1);
    return (unsigned short)(u >> 16);
}
__device__ __forceinline__ float bf2f(unsigned short h) {
    return __uint_as_float(((unsigned)h) << 16);
}

// ---------------------------------------------------------------------------
// K1: fc1 over the time axis -> y bf16.
// y[b,n,i] = sum_t x[b,t,i] * fc1_w[n,t] + fc1_b[n]
// ---------------------------------------------------------------------------
__global__ void fc1_kernel(const float* __restrict__ x,
                           const float* __restrict__ fc1_w,
                           const float* __restrict__ fc1_b,
                           unsigned short* __restrict__ y) {
    __shared__ float w8[8][WS_DIM];
    const int b = blockIdx.y;
    const int n0 = blockIdx.x * 8;
    const int tid = threadIdx.x;

    for (int idx = tid; idx < 8 * WS_DIM; idx += 256) {
        w8[idx / WS_DIM][idx % WS_DIM] =
            fc1_w[(size_t)(n0 + idx / WS_DIM) * WS_DIM + (idx % WS_DIM)];
    }
    __syncthreads();

    const int i = tid;  // blockDim.x == 256 == I_DIM
    float acc[8];
#pragma unroll
    for (int k = 0; k < 8; ++k) acc[k] = fc1_b[n0 + k];

    const float* xb = x + (size_t)b * WS_DIM * I_DIM + i;
    for (int t = 0; t < WS_DIM; ++t) {
        float xv = xb[(size_t)t * I_DIM];
#pragma unroll
        for (int k = 0; k < 8; ++k) acc[k] += xv * w8[k][t];
    }

    unsigned short* yb = y + ((size_t)b * NWS + n0) * I_DIM + i;
#pragma unroll
    for (int k = 0; k < 8; ++k) yb[(size_t)k * I_DIM] = f2bf(acc[k]);
}

// ---------------------------------------------------------------------------
// Persistent cooperative GRU recurrence.
// 256 blocks x 256 threads (1 block/CU). Block = (bt 0..15, jt 0..15):
//   batch rows b0=bt*32 (32 rows), j slice j0=jt*32 (32 j x 3 gates = 96 N).
// Weights bf16 in LDS, layout [ks][n][q] with XOR swizzle:
//   byte = ks*6144 + ((n*64 + q*16) ^ ((n&7)<<4)) + e*2,  k = ks*32+q*8+e.
// Wave w: wm=w&1 -> M-tile (16 batch), jh=w>>1 -> jj half (16 cols).
// Per wave per k-step: 1 A-frag (global bf16), 3 B-frags (LDS), 3 MFMA.
// Input-K (8 ks) accumulates into aR/aZ/aN, hidden-K (16 ks) into hR/hZ/hN
// so the n-gate keeps gx and gh separate. Gating fully in-lane.
// ---------------------------------------------------------------------------
#define LDSB (24 * 96 * 64)  // 147456 bytes

__global__ void __launch_bounds__(256, 1)
gru_persist(const unsigned short* __restrict__ y,  // [B,NWS,I] bf16
            const float* __restrict__ Wih, const float* __restrict__ bih,
            const float* __restrict__ Whh, const float* __restrict__ bhh,
            unsigned short* __restrict__ hA,   // ping [B,H] bf16 (pre-zeroed)
            unsigned short* __restrict__ hB,   // pong [B,H] bf16
            unsigned short* __restrict__ hseq) {  // [B,PRE,H] bf16
    extern __shared__ char lds[];
    const int tid = threadIdx.x;
    const int lane = tid & 63;
    const int w = tid >> 6;
    const int wm = w & 1;
    const int jh = w >> 1;
    const int bt = blockIdx.x & 15;
    const int jt = blockIdx.x >> 4;
    const int b0 = bt * 32;
    const int j0 = jt * 32;

    // ---- one-time weight preload into swizzled LDS ----
    for (int idx = tid; idx < 96 * 768; idx += 256) {
        int n = idx / 768, k = idx % 768;  // k fastest -> coalesced global reads
        int g = n >> 5, jj = n & 31;
        int srow = g * H_DIM + j0 + jj;
        float wv = (k < I_DIM) ? Wih[(size_t)srow * I_DIM + k]
                               : Whh[(size_t)srow * H_DIM + (k - I_DIM)];
        int ks = k >> 5, q = (k & 31) >> 3, e = k & 7;
        int byteoff = ks * 6144 + (((n * 64 + q * 16) ^ ((n & 7) << 4)) + e * 2);
        *(unsigned short*)(lds + byteoff) = f2bf(wv);
    }

    const int row16 = lane & 15;
    const int qg = lane >> 4;
    const int bbA = b0 + wm * 16 + row16;  // A-fragment source row
    const int jj = jh * 16 + row16;        // C col within 32-j slice
    const int j = j0 + jj;

    const int n0r = 0 * 32 + jj;
    const int n1r = 1 * 32 + jj;
    const int n2r = 2 * 32 + jj;
    const int bof0 = (n0r * 64 + qg * 16) ^ ((n0r & 7) << 4);
    const int bof1 = (n1r * 64 + qg * 16) ^ ((n1r & 7) << 4);
    const int bof2 = (n2r * 64 + qg * 16) ^ ((n2r & 7) << 4);

    const float br_i = bih[j], br_h = bhh[j];
    const float bz_i = bih[H_DIM + j], bz_h = bhh[H_DIM + j];
    const float bn_i = bih[2 * H_DIM + j], bn_h = bhh[2 * H_DIM + j];

    __syncthreads();

    cg::grid_group grid = cg::this_grid();

    const unsigned short* ybase = y + (size_t)bbA * NWS * I_DIM + qg * 8;

    for (int step = 0; step < NWS; ++step) {
        const unsigned short* hin = (step & 1) ? hB : hA;
        unsigned short* hout      = (step & 1) ? hA : hB;

        f32x4 aR = {br_i, br_i, br_i, br_i};
        f32x4 aZ = {bz_i, bz_i, bz_i, bz_i};
        f32x4 aN = {bn_i, bn_i, bn_i, bn_i};
        f32x4 hR = {br_h, br_h, br_h, br_h};
        f32x4 hZ = {bz_h, bz_h, bz_h, bz_h};
        f32x4 hN = {bn_h, bn_h, bn_h, bn_h};

        const unsigned short* yp = ybase + (size_t)step * I_DIM;
#pragma unroll
        for (int ks = 0; ks < 8; ++ks) {
            short8 af = *(const short8*)(yp + ks * 32);
            short8 bf0 = *(const short8*)(lds + ks * 6144 + bof0);
            short8 bf1 = *(const short8*)(lds + ks * 6144 + bof1);
            short8 bf2 = *(const short8*)(lds + ks * 6144 + bof2);
            aR = MFMA16(af, bf0, aR);
            aZ = MFMA16(af, bf1, aZ);
            aN = MFMA16(af, bf2, aN);
        }
        const unsigned short* hpnt = hin + (size_t)bbA * H_DIM + qg * 8;
#pragma unroll
        for (int ks = 0; ks < 16; ++ks) {
            short8 af = *(const short8*)(hpnt + ks * 32);
            short8 bf0 = *(const short8*)(lds + (8 + ks) * 6144 + bof0);
            short8 bf1 = *(const short8*)(lds + (8 + ks) * 6144 + bof1);
            short8 bf2 = *(const short8*)(lds + (8 + ks) * 6144 + bof2);
            hR = MFMA16(af, bf0, hR);
            hZ = MFMA16(af, bf1, hZ);
            hN = MFMA16(af, bf2, hN);
        }

        // C/D layout: col = lane&15 (= jj), row = qg*4 + r (within 16-row tile)
#pragma unroll
        for (int r = 0; r < 4; ++r) {
            int brow = b0 + wm * 16 + qg * 4 + r;
            float pr = aR[r] + hR[r];
            float pz = aZ[r] + hZ[r];
            float rr = 1.f / (1.f + __expf(-pr));
            float zz = 1.f / (1.f + __expf(-pz));
            float pn = aN[r] + rr * hN[r];
            float ax = fabsf(pn);
            float e2 = __expf(2.f * ax);
            float nn = copysignf(1.f - 2.f / (e2 + 1.f), pn);
            float hprev = bf2f(hin[(size_t)brow * H_DIM + j]);
            float hnew = (1.f - zz) * nn + zz * hprev;
            unsigned short hbf = f2bf(hnew);
            hout[(size_t)brow * H_DIM + j] = hbf;
            if (step >= SEQ0) {
                hseq[((size_t)brow * PRE + (step - SEQ0)) * H_DIM + j] = hbf;
            }
        }
        __threadfence();
        grid.sync();
    }
}

// ---------------------------------------------------------------------------
// fc2 as bf16 MFMA GEMM: out[12288,256] = hseq[12288,512] * w2[256,512]^T + b
// grid (192, 4), 256 threads, wave tile 32x32 (2Mt x 2Nt), frags from global.
// ---------------------------------------------------------------------------
__global__ void __launch_bounds__(256)
fc2_mfma(const unsigned short* __restrict__ hseq,
         const unsigned short* __restrict__ w2,
         const float* __restrict__ bias,
         float* __restrict__ out) {
    const int tid = threadIdx.x;
    const int lane = tid & 63;
    const int w = tid >> 6;
    const int wm = w & 1, wn = w >> 1;
    const int row16 = lane & 15, qg = lane >> 4;
    const int mbase = blockIdx.x * 64 + wm * 32;
    const int nbase = blockIdx.y * 64 + wn * 32;

    f32x4 acc00 = {0.f, 0.f, 0.f, 0.f}, acc01 = {0.f, 0.f, 0.f, 0.f};
    f32x4 acc10 = {0.f, 0.f, 0.f, 0.f}, acc11 = {0.f, 0.f, 0.f, 0.f};

    const unsigned short* ap0 = hseq + (size_t)(mbase + row16) * H_DIM + qg * 8;
    const unsigned short* ap1 = hseq + (size_t)(mbase + 16 + row16) * H_DIM + qg * 8;
    const unsigned short* bp0 = w2 + (size_t)(nbase + row16) * H_DIM + qg * 8;
    const unsigned short* bp1 = w2 + (size_t)(nbase + 16 + row16) * H_DIM + qg * 8;
#pragma unroll
    for (int ks = 0; ks < 16; ++ks) {
        short8 a0 = *(const short8*)(ap0 + ks * 32);
        short8 a1 = *(const short8*)(ap1 + ks * 32);
        short8 b0 = *(const short8*)(bp0 + ks * 32);
        short8 b1 = *(const short8*)(bp1 + ks * 32);
        acc00 = MFMA16(a0, b0, acc00);
        acc01 = MFMA16(a0, b1, acc01);
        acc10 = MFMA16(a1, b0, acc10);
        acc11 = MFMA16(a1, b1, acc11);
    }

#pragma unroll
    for (int r = 0; r < 4; ++r) {
        int r0 = mbase + qg * 4 + r;
        int r1 = r0 + 16;
        int c0 = nbase + row16;
        int c1 = c0 + 16;
        out[(size_t)r0 * I_DIM + c0] = acc00[r] + bias[c0];
        out[(size_t)r0 * I_DIM + c1] = acc01[r] + bias[c1];
        out[(size_t)r1 * I_DIM + c0] = acc10[r] + bias[c0];
        out[(size_t)r1 * I_DIM + c1] = acc11[r] + bias[c1];
    }
}

__global__ void cvt_w2(const float* __restrict__ w, unsigned short* __restrict__ o, int n) {
    int i = blockIdx.x * 256 + threadIdx.x;
    if (i < n) o[i] = f2bf(w[i]);
}

extern "C" void kernel_launch(void* const* d_in, const int* in_sizes, int n_in,
                              void* d_out, int out_size, void* d_ws, size_t ws_size,
                              hipStream_t stream) {
    const float* x     = (const float*)d_in[0];
    const float* fc1_w = (const float*)d_in[1];
    const float* fc1_b = (const float*)d_in[2];
    const float* W_ih  = (const float*)d_in[3];
    const float* W_hh  = (const float*)d_in[4];
    const float* b_ih  = (const float*)d_in[5];
    const float* b_hh  = (const float*)d_in[6];
    const float* fc2_w = (const float*)d_in[7];
    const float* fc2_b = (const float*)d_in[8];
    float* out = (float*)d_out;

    unsigned short* ws = (unsigned short*)d_ws;
    unsigned short* y_bf  = ws;                                        // 8388608
    unsigned short* h0    = y_bf + (size_t)B_DIM * NWS * I_DIM;        // 262144
    unsigned short* h1    = h0 + (size_t)B_DIM * H_DIM;                // 262144
    unsigned short* hseq  = h1 + (size_t)B_DIM * H_DIM;                // 6291456
    unsigned short* w2_bf = hseq + (size_t)B_DIM * PRE * H_DIM;        // 131072

    hipMemsetAsync(h0, 0, (size_t)B_DIM * H_DIM * sizeof(unsigned short), stream);

    cvt_w2<<<dim3((I_DIM * H_DIM + 255) / 256), dim3(256), 0, stream>>>(
        fc2_w, w2_bf, I_DIM * H_DIM);

    fc1_kernel<<<dim3(NWS / 8, B_DIM), dim3(256), 0, stream>>>(x, fc1_w, fc1_b, y_bf);

    hipFuncSetAttribute((const void*)gru_persist,
                        hipFuncAttributeMaxDynamicSharedMemorySize, LDSB);

    void* args[] = {(void*)&y_bf, (void*)&W_ih, (void*)&b_ih, (void*)&W_hh,
                    (void*)&b_hh, (void*)&h0, (void*)&h1, (void*)&hseq};
    hipLaunchCooperativeKernel((const void*)gru_persist, dim3(256), dim3(256),
                               args, LDSB, stream);

    fc2_mfma<<<dim3((B_DIM * PRE) / 64, I_DIM / 64), dim3(256), 0, stream>>>(
        hseq, w2_bf, fc2_b, out);
}

// Round 3
// 854.360 us; speedup vs baseline: 6.0084x; 4.3816x over previous
//
#include <hip/hip_runtime.h>
#include <math.h>

#define B_DIM 512
#define WS_DIM 128
#define I_DIM 256
#define H_DIM 512
#define NWS 64
#define PRE 24
#define SEQ0 (NWS - PRE)  // 40

typedef __attribute__((ext_vector_type(8))) short short8;
typedef __attribute__((ext_vector_type(4))) float f32x4;

#define MFMA16(a, b, c) __builtin_amdgcn_mfma_f32_16x16x32_bf16((a), (b), (c), 0, 0, 0)

__device__ __forceinline__ unsigned short f2bf(float f) {
    unsigned u = __float_as_uint(f);
    u += 0x7FFF + ((u >> 16) & 1);
    return (unsigned short)(u >> 16);
}
__device__ __forceinline__ float bf2f(unsigned short h) {
    return __uint_as_float(((unsigned)h) << 16);
}

// Device-coherent (MALL) accesses: bypass the non-coherent per-XCD L2s.
__device__ __forceinline__ unsigned ld_dev(const unsigned* p) {
    return __hip_atomic_load((unsigned*)p, __ATOMIC_RELAXED, __HIP_MEMORY_SCOPE_AGENT);
}
__device__ __forceinline__ void st_dev(unsigned* p, unsigned v) {
    __hip_atomic_store(p, v, __ATOMIC_RELAXED, __HIP_MEMORY_SCOPE_AGENT);
}

// ---------------------------------------------------------------------------
// K1: fc1 over the time axis -> y bf16.
// ---------------------------------------------------------------------------
__global__ void fc1_kernel(const float* __restrict__ x,
                           const float* __restrict__ fc1_w,
                           const float* __restrict__ fc1_b,
                           unsigned short* __restrict__ y) {
    __shared__ float w8[8][WS_DIM];
    const int b = blockIdx.y;
    const int n0 = blockIdx.x * 8;
    const int tid = threadIdx.x;

    for (int idx = tid; idx < 8 * WS_DIM; idx += 256) {
        w8[idx / WS_DIM][idx % WS_DIM] =
            fc1_w[(size_t)(n0 + idx / WS_DIM) * WS_DIM + (idx % WS_DIM)];
    }
    __syncthreads();

    const int i = tid;
    float acc[8];
#pragma unroll
    for (int k = 0; k < 8; ++k) acc[k] = fc1_b[n0 + k];

    const float* xb = x + (size_t)b * WS_DIM * I_DIM + i;
    for (int t = 0; t < WS_DIM; ++t) {
        float xv = xb[(size_t)t * I_DIM];
#pragma unroll
        for (int k = 0; k < 8; ++k) acc[k] += xv * w8[k][t];
    }

    unsigned short* yb = y + ((size_t)b * NWS + n0) * I_DIM + i;
#pragma unroll
    for (int k = 0; k < 8; ++k) yb[(size_t)k * I_DIM] = f2bf(acc[k]);
}

// ---------------------------------------------------------------------------
// Persistent GRU recurrence, flag-synced (no grid.sync).
// 256 blocks x 256 threads (1 block/CU via 147KB LDS; cooperative launch
// guarantees co-residency for the spin protocol).
// Block (bt = blockIdx&15, jt = blockIdx>>4): batch rows bt*32.., j cols jt*32..
// Sync: only the 16 blocks sharing bt exchange h. h crosses blocks through
// the device coherence point (relaxed agent atomics), flags likewise.
// ---------------------------------------------------------------------------
#define LDSB (24 * 96 * 64)  // 147456 bytes

__global__ void __launch_bounds__(256, 1)
gru_persist(const unsigned short* __restrict__ y,  // [B,NWS,I] bf16
            const float* __restrict__ Wih, const float* __restrict__ bih,
            const float* __restrict__ Whh, const float* __restrict__ bhh,
            unsigned short* __restrict__ hA,   // ping [B,H] bf16 (pre-zeroed)
            unsigned short* __restrict__ hB,   // pong [B,H] bf16
            unsigned short* __restrict__ hseq, // [B,PRE,H] bf16
            unsigned* __restrict__ flags) {    // [16][NWS] (pre-zeroed)
    extern __shared__ char lds[];
    const int tid = threadIdx.x;
    const int lane = tid & 63;
    const int w = tid >> 6;
    const int wm = w & 1;
    const int jh = w >> 1;
    const int bt = blockIdx.x & 15;
    const int jt = blockIdx.x >> 4;
    const int b0 = bt * 32;
    const int j0 = jt * 32;

    // ---- one-time weight preload into swizzled LDS ----
    for (int idx = tid; idx < 96 * 768; idx += 256) {
        int n = idx / 768, k = idx % 768;
        int g = n >> 5, jj = n & 31;
        int srow = g * H_DIM + j0 + jj;
        float wv = (k < I_DIM) ? Wih[(size_t)srow * I_DIM + k]
                               : Whh[(size_t)srow * H_DIM + (k - I_DIM)];
        int ks = k >> 5, q = (k & 31) >> 3, e = k & 7;
        int byteoff = ks * 6144 + (((n * 64 + q * 16) ^ ((n & 7) << 4)) + e * 2);
        *(unsigned short*)(lds + byteoff) = f2bf(wv);
    }

    const int row16 = lane & 15;
    const int qg = lane >> 4;
    const int bbA = b0 + wm * 16 + row16;  // A-fragment source row
    const int jj = jh * 16 + row16;        // C col within 32-j slice
    const int j = j0 + jj;

    const int n0r = 0 * 32 + jj;
    const int n1r = 1 * 32 + jj;
    const int n2r = 2 * 32 + jj;
    const int bof0 = (n0r * 64 + qg * 16) ^ ((n0r & 7) << 4);
    const int bof1 = (n1r * 64 + qg * 16) ^ ((n1r & 7) << 4);
    const int bof2 = (n2r * 64 + qg * 16) ^ ((n2r & 7) << 4);

    const float br_i = bih[j], br_h = bhh[j];
    const float bz_i = bih[H_DIM + j], bz_h = bhh[H_DIM + j];
    const float bn_i = bih[2 * H_DIM + j], bn_h = bhh[2 * H_DIM + j];

    __syncthreads();

    const unsigned short* ybase = y + (size_t)bbA * NWS * I_DIM + qg * 8;

    for (int step = 0; step < NWS; ++step) {
        const unsigned short* hin = (step & 1) ? hB : hA;
        unsigned short* hout      = (step & 1) ? hA : hB;

        f32x4 aR = {br_i, br_i, br_i, br_i};
        f32x4 aZ = {bz_i, bz_i, bz_i, bz_i};
        f32x4 aN = {bn_i, bn_i, bn_i, bn_i};
        f32x4 hR = {br_h, br_h, br_h, br_h};
        f32x4 hZ = {bz_h, bz_h, bz_h, bz_h};
        f32x4 hN = {bn_h, bn_h, bn_h, bn_h};

        // ---- input phase first (y only): hides flag-propagation latency ----
        const unsigned short* yp = ybase + (size_t)step * I_DIM;
#pragma unroll
        for (int ks = 0; ks < 8; ++ks) {
            short8 af = *(const short8*)(yp + ks * 32);
            short8 bf0 = *(const short8*)(lds + ks * 6144 + bof0);
            short8 bf1 = *(const short8*)(lds + ks * 6144 + bof1);
            short8 bf2 = *(const short8*)(lds + ks * 6144 + bof2);
            aR = MFMA16(af, bf0, aR);
            aZ = MFMA16(af, bf1, aZ);
            aN = MFMA16(af, bf2, aN);
        }

        // ---- wait for previous step's h from the other 15 blocks of bt ----
        if (step > 0) {
            if (tid == 0) {
                unsigned* f = &flags[bt * NWS + (step - 1)];
                while (__hip_atomic_load(f, __ATOMIC_RELAXED,
                                         __HIP_MEMORY_SCOPE_AGENT) < 16u)
                    __builtin_amdgcn_s_sleep(1);
            }
            __syncthreads();
        }

        // ---- hidden phase: h via device-coherent loads ----
        const unsigned* hp32 = (const unsigned*)(hin + (size_t)bbA * H_DIM) + qg * 4;
#pragma unroll
        for (int ks = 0; ks < 16; ++ks) {
            union { unsigned u[4]; short8 s; } t;
            t.u[0] = ld_dev(hp32 + ks * 16 + 0);
            t.u[1] = ld_dev(hp32 + ks * 16 + 1);
            t.u[2] = ld_dev(hp32 + ks * 16 + 2);
            t.u[3] = ld_dev(hp32 + ks * 16 + 3);
            short8 af = t.s;
            short8 bf0 = *(const short8*)(lds + (8 + ks) * 6144 + bof0);
            short8 bf1 = *(const short8*)(lds + (8 + ks) * 6144 + bof1);
            short8 bf2 = *(const short8*)(lds + (8 + ks) * 6144 + bof2);
            hR = MFMA16(af, bf0, hR);
            hZ = MFMA16(af, bf1, hZ);
            hN = MFMA16(af, bf2, hN);
        }

        // ---- epilogue: gating; C/D layout col=lane&15, row=qg*4+r ----
#pragma unroll
        for (int r = 0; r < 4; ++r) {
            int brow = b0 + wm * 16 + qg * 4 + r;
            float pr = aR[r] + hR[r];
            float pz = aZ[r] + hZ[r];
            float rr = 1.f / (1.f + __expf(-pr));
            float zz = 1.f / (1.f + __expf(-pz));
            float pn = aN[r] + rr * hN[r];
            float ax = fabsf(pn);
            float e2 = __expf(2.f * ax);
            float nn = copysignf(1.f - 2.f / (e2 + 1.f), pn);
            unsigned hw = ld_dev((const unsigned*)hin + ((size_t)brow * H_DIM + j) / 2);
            float hprev = bf2f((unsigned short)((j & 1) ? (hw >> 16) : (hw & 0xffff)));
            float hnew = (1.f - zz) * nn + zz * hprev;
            unsigned short hbf = f2bf(hnew);
            // pair lanes (j, j^1) -> one dword device-coherent store by even lane
            unsigned v = (unsigned)hbf;
            unsigned part = __shfl_xor(v, 1);
            if ((lane & 1) == 0) {
                st_dev((unsigned*)hout + ((size_t)brow * H_DIM + j) / 2,
                       v | (part << 16));
            }
            if (step >= SEQ0) {
                hseq[((size_t)brow * PRE + (step - SEQ0)) * H_DIM + j] = hbf;
            }
        }

        // ---- publish our slice for this step ----
        asm volatile("s_waitcnt vmcnt(0)" ::: "memory");
        __syncthreads();
        if (tid == 0 && step + 1 < NWS) {
            __hip_atomic_fetch_add(&flags[bt * NWS + step], 1u,
                                   __ATOMIC_RELAXED, __HIP_MEMORY_SCOPE_AGENT);
        }
    }
}

// ---------------------------------------------------------------------------
// fc2 as bf16 MFMA GEMM: out[12288,256] = hseq[12288,512] * w2[256,512]^T + b
// ---------------------------------------------------------------------------
__global__ void __launch_bounds__(256)
fc2_mfma(const unsigned short* __restrict__ hseq,
         const unsigned short* __restrict__ w2,
         const float* __restrict__ bias,
         float* __restrict__ out) {
    const int tid = threadIdx.x;
    const int lane = tid & 63;
    const int w = tid >> 6;
    const int wm = w & 1, wn = w >> 1;
    const int row16 = lane & 15, qg = lane >> 4;
    const int mbase = blockIdx.x * 64 + wm * 32;
    const int nbase = blockIdx.y * 64 + wn * 32;

    f32x4 acc00 = {0.f, 0.f, 0.f, 0.f}, acc01 = {0.f, 0.f, 0.f, 0.f};
    f32x4 acc10 = {0.f, 0.f, 0.f, 0.f}, acc11 = {0.f, 0.f, 0.f, 0.f};

    const unsigned short* ap0 = hseq + (size_t)(mbase + row16) * H_DIM + qg * 8;
    const unsigned short* ap1 = hseq + (size_t)(mbase + 16 + row16) * H_DIM + qg * 8;
    const unsigned short* bp0 = w2 + (size_t)(nbase + row16) * H_DIM + qg * 8;
    const unsigned short* bp1 = w2 + (size_t)(nbase + 16 + row16) * H_DIM + qg * 8;
#pragma unroll
    for (int ks = 0; ks < 16; ++ks) {
        short8 a0 = *(const short8*)(ap0 + ks * 32);
        short8 a1 = *(const short8*)(ap1 + ks * 32);
        short8 b0 = *(const short8*)(bp0 + ks * 32);
        short8 b1 = *(const short8*)(bp1 + ks * 32);
        acc00 = MFMA16(a0, b0, acc00);
        acc01 = MFMA16(a0, b1, acc01);
        acc10 = MFMA16(a1, b0, acc10);
        acc11 = MFMA16(a1, b1, acc11);
    }

#pragma unroll
    for (int r = 0; r < 4; ++r) {
        int r0 = mbase + qg * 4 + r;
        int r1 = r0 + 16;
        int c0 = nbase + row16;
        int c1 = c0 + 16;
        out[(size_t)r0 * I_DIM + c0] = acc00[r] + bias[c0];
        out[(size_t)r0 * I_DIM + c1] = acc01[r] + bias[c1];
        out[(size_t)r1 * I_DIM + c0] = acc10[r] + bias[c0];
        out[(size_t)r1 * I_DIM + c1] = acc11[r] + bias[c1];
    }
}

__global__ void cvt_w2(const float* __restrict__ w, unsigned short* __restrict__ o, int n) {
    int i = blockIdx.x * 256 + threadIdx.x;
    if (i < n) o[i] = f2bf(w[i]);
}

extern "C" void kernel_launch(void* const* d_in, const int* in_sizes, int n_in,
                              void* d_out, int out_size, void* d_ws, size_t ws_size,
                              hipStream_t stream) {
    const float* x     = (const float*)d_in[0];
    const float* fc1_w = (const float*)d_in[1];
    const float* fc1_b = (const float*)d_in[2];
    const float* W_ih  = (const float*)d_in[3];
    const float* W_hh  = (const float*)d_in[4];
    const float* b_ih  = (const float*)d_in[5];
    const float* b_hh  = (const float*)d_in[6];
    const float* fc2_w = (const float*)d_in[7];
    const float* fc2_b = (const float*)d_in[8];
    float* out = (float*)d_out;

    unsigned short* ws = (unsigned short*)d_ws;
    unsigned short* y_bf  = ws;                                        // 8388608
    unsigned short* h0    = y_bf + (size_t)B_DIM * NWS * I_DIM;        // 262144
    unsigned short* h1    = h0 + (size_t)B_DIM * H_DIM;                // 262144
    unsigned short* hseq  = h1 + (size_t)B_DIM * H_DIM;                // 6291456
    unsigned short* w2_bf = hseq + (size_t)B_DIM * PRE * H_DIM;        // 131072
    unsigned* flags = (unsigned*)(w2_bf + (size_t)I_DIM * H_DIM);      // 16*64 u32

    hipMemsetAsync(h0, 0, (size_t)B_DIM * H_DIM * sizeof(unsigned short), stream);
    hipMemsetAsync(flags, 0, 16 * NWS * sizeof(unsigned), stream);

    cvt_w2<<<dim3((I_DIM * H_DIM + 255) / 256), dim3(256), 0, stream>>>(
        fc2_w, w2_bf, I_DIM * H_DIM);

    fc1_kernel<<<dim3(NWS / 8, B_DIM), dim3(256), 0, stream>>>(x, fc1_w, fc1_b, y_bf);

    hipFuncSetAttribute((const void*)gru_persist,
                        hipFuncAttributeMaxDynamicSharedMemorySize, LDSB);

    void* args[] = {(void*)&y_bf, (void*)&W_ih, (void*)&b_ih, (void*)&W_hh,
                    (void*)&b_hh, (void*)&h0, (void*)&h1, (void*)&hseq,
                    (void*)&flags};
    hipLaunchCooperativeKernel((const void*)gru_persist, dim3(256), dim3(256),
                               args, LDSB, stream);

    fc2_mfma<<<dim3((B_DIM * PRE) / 64, I_DIM / 64), dim3(256), 0, stream>>>(
        hseq, w2_bf, fc2_b, out);
}

// Round 8
// 589.192 us; speedup vs baseline: 8.7125x; 1.4501x over previous
//
#include <hip/hip_runtime.h>
#include <math.h>

#define B_DIM 512
#define WS_DIM 128
#define I_DIM 256
#define H_DIM 512
#define NWS 64
#define PRE 24
#define SEQ0 (NWS - PRE)  // 40

typedef __attribute__((ext_vector_type(8))) short short8;
typedef __attribute__((ext_vector_type(4))) float f32x4;

#define MFMA16(a, b, c) __builtin_amdgcn_mfma_f32_16x16x32_bf16((a), (b), (c), 0, 0, 0)

__device__ __forceinline__ unsigned short f2bf(float f) {
    unsigned u = __float_as_uint(f);
    u += 0x7FFF + ((u >> 16) & 1);
    return (unsigned short)(u >> 16);
}
__device__ __forceinline__ float bf2f(unsigned short h) {
    return __uint_as_float(((unsigned)h) << 16);
}

// Device-coherent (MALL) accesses: bypass the non-coherent per-XCD L2s.
__device__ __forceinline__ unsigned ld_dev(const unsigned* p) {
    return __hip_atomic_load((unsigned*)p, __ATOMIC_RELAXED, __HIP_MEMORY_SCOPE_AGENT);
}
__device__ __forceinline__ unsigned long long ld_dev64(const unsigned long long* p) {
    return __hip_atomic_load((unsigned long long*)p, __ATOMIC_RELAXED, __HIP_MEMORY_SCOPE_AGENT);
}
__device__ __forceinline__ void st_dev(unsigned* p, unsigned v) {
    __hip_atomic_store(p, v, __ATOMIC_RELAXED, __HIP_MEMORY_SCOPE_AGENT);
}

// ---------------------------------------------------------------------------
// K1: fc1 over the time axis -> y bf16.   (round-3 proven version)
// ---------------------------------------------------------------------------
__global__ void fc1_kernel(const float* __restrict__ x,
                           const float* __restrict__ fc1_w,
                           const float* __restrict__ fc1_b,
                           unsigned short* __restrict__ y) {
    __shared__ float w8[8][WS_DIM];
    const int b = blockIdx.y;
    const int n0 = blockIdx.x * 8;
    const int tid = threadIdx.x;

    for (int idx = tid; idx < 8 * WS_DIM; idx += 256) {
        w8[idx / WS_DIM][idx % WS_DIM] =
            fc1_w[(size_t)(n0 + idx / WS_DIM) * WS_DIM + (idx % WS_DIM)];
    }
    __syncthreads();

    const int i = tid;
    float acc[8];
#pragma unroll
    for (int k = 0; k < 8; ++k) acc[k] = fc1_b[n0 + k];

    const float* xb = x + (size_t)b * WS_DIM * I_DIM + i;
    for (int t = 0; t < WS_DIM; ++t) {
        float xv = xb[(size_t)t * I_DIM];
#pragma unroll
        for (int k = 0; k < 8; ++k) acc[k] += xv * w8[k][t];
    }

    unsigned short* yb = y + ((size_t)b * NWS + n0) * I_DIM + i;
#pragma unroll
    for (int k = 0; k < 8; ++k) yb[(size_t)k * I_DIM] = f2bf(acc[k]);
}

// ---------------------------------------------------------------------------
// Persistent GRU recurrence — BISECTION ROUND: round 7 with Whh-VGPR REVERTED.
// All weights in LDS exactly as round 3 (147KB dynamic, same swizzle fill).
// Kept from round 7 (set T): y-prefetch dbuf, hf batch loads, hprev early,
// hseq after publish, STEP lambda, round-3 sync skeleton.
// ---------------------------------------------------------------------------
#define LDSB (24 * 96 * 64)  // 147456 bytes

__global__ void __launch_bounds__(256, 1)
gru_persist(const unsigned short* __restrict__ y,  // [B,NWS,I] bf16
            const float* __restrict__ Wih, const float* __restrict__ bih,
            const float* __restrict__ Whh, const float* __restrict__ bhh,
            unsigned short* __restrict__ hA,   // ping [B,H] bf16 (pre-zeroed)
            unsigned short* __restrict__ hB,   // pong
            unsigned short* __restrict__ hseq, // [B,PRE,H] bf16
            unsigned* __restrict__ flags) {    // [16][NWS] (pre-zeroed)
    extern __shared__ char lds[];
    const int tid = threadIdx.x;
    const int lane = tid & 63;
    const int w = tid >> 6;
    const int wm = w & 1;
    const int jh = w >> 1;
    const int bt = blockIdx.x & 15;
    const int jt = blockIdx.x >> 4;
    const int b0 = bt * 32;
    const int j0 = jt * 32;

    // ---- one-time weight preload into swizzled LDS (round-3 verbatim) ----
    for (int idx = tid; idx < 96 * 768; idx += 256) {
        int n = idx / 768, k = idx % 768;
        int g = n >> 5, jj = n & 31;
        int srow = g * H_DIM + j0 + jj;
        float wv = (k < I_DIM) ? Wih[(size_t)srow * I_DIM + k]
                               : Whh[(size_t)srow * H_DIM + (k - I_DIM)];
        int ks = k >> 5, q = (k & 31) >> 3, e = k & 7;
        int byteoff = ks * 6144 + (((n * 64 + q * 16) ^ ((n & 7) << 4)) + e * 2);
        *(unsigned short*)(lds + byteoff) = f2bf(wv);
    }

    const int row16 = lane & 15;
    const int qg = lane >> 4;
    const int bbA = b0 + wm * 16 + row16;  // A-fragment source row
    const int jj = jh * 16 + row16;        // C col within 32-j slice
    const int j = j0 + jj;

    const int n0r = jj, n1r = 32 + jj, n2r = 64 + jj;
    const int bof0 = (n0r * 64 + qg * 16) ^ ((n0r & 7) << 4);
    const int bof1 = (n1r * 64 + qg * 16) ^ ((n1r & 7) << 4);
    const int bof2 = (n2r * 64 + qg * 16) ^ ((n2r & 7) << 4);

    const float br_i = bih[j], br_h = bhh[j];
    const float bz_i = bih[H_DIM + j], bz_h = bhh[H_DIM + j];
    const float bn_i = bih[2 * H_DIM + j], bn_h = bhh[2 * H_DIM + j];

    __syncthreads();  // LDS weights ready (one-time)

    const unsigned short* ybase = y + (size_t)bbA * NWS * I_DIM + qg * 8;

    short8 yf0[8], yf1[8];
#pragma unroll
    for (int ks = 0; ks < 8; ++ks) yf0[ks] = *(const short8*)(ybase + ks * 32);

    auto STEP = [&](int step, short8(&yc)[8], short8(&yn)[8]) {
        const unsigned short* hin = (step & 1) ? hB : hA;
        unsigned short* hout      = (step & 1) ? hA : hB;

        f32x4 aR = {br_i, br_i, br_i, br_i};
        f32x4 aZ = {bz_i, bz_i, bz_i, bz_i};
        f32x4 aN = {bn_i, bn_i, bn_i, bn_i};

        // ---- input phase (no h dependency) ----
#pragma unroll
        for (int ks = 0; ks < 8; ++ks) {
            short8 bf0 = *(const short8*)(lds + ks * 6144 + bof0);
            short8 bf1 = *(const short8*)(lds + ks * 6144 + bof1);
            short8 bf2 = *(const short8*)(lds + ks * 6144 + bof2);
            aR = MFMA16(yc[ks], bf0, aR);
            aZ = MFMA16(yc[ks], bf1, aZ);
            aN = MFMA16(yc[ks], bf2, aN);
        }

        // ---- prefetch next step's y fragments (overlaps the wait) ----
        int sn = (step + 1 < NWS) ? step + 1 : NWS - 1;
        const unsigned short* ypn = ybase + (size_t)sn * I_DIM;
#pragma unroll
        for (int ks = 0; ks < 8; ++ks) yn[ks] = *(const short8*)(ypn + ks * 32);

        // ---- wait (round-3 proven): tid0 spins on block counter, barrier ----
        if (step > 0) {
            if (tid == 0) {
                unsigned* f = &flags[bt * NWS + (step - 1)];
                while (__hip_atomic_load(f, __ATOMIC_RELAXED,
                                         __HIP_MEMORY_SCOPE_AGENT) < 16u)
                    __builtin_amdgcn_s_sleep(1);
            }
            __syncthreads();
        }

        // ---- h fragment loads (MALL-coherent) ----
        const unsigned long long* hq = (const unsigned long long*)(hin + (size_t)bbA * H_DIM);
        short8 hf[16];
#pragma unroll
        for (int ks = 0; ks < 16; ++ks) {
            union { unsigned long long u[2]; short8 s; } t;
            t.u[0] = ld_dev64(hq + ks * 8 + qg * 2);
            t.u[1] = ld_dev64(hq + ks * 8 + qg * 2 + 1);
            hf[ks] = t.s;
        }
        // hprev for the epilogue (overlaps MFMA below)
        unsigned hw[4];
        const unsigned* h32 = (const unsigned*)hin;
#pragma unroll
        for (int r = 0; r < 4; ++r) {
            int brow = b0 + wm * 16 + qg * 4 + r;
            hw[r] = ld_dev(h32 + brow * (H_DIM / 2) + (j >> 1));
        }

        // ---- hidden phase: B-operands from LDS (round-3 source) ----
        f32x4 hR = {br_h, br_h, br_h, br_h};
        f32x4 hZ = {bz_h, bz_h, bz_h, bz_h};
        f32x4 hN = {bn_h, bn_h, bn_h, bn_h};
#pragma unroll
        for (int ks = 0; ks < 16; ++ks) {
            short8 bf0 = *(const short8*)(lds + (8 + ks) * 6144 + bof0);
            short8 bf1 = *(const short8*)(lds + (8 + ks) * 6144 + bof1);
            short8 bf2 = *(const short8*)(lds + (8 + ks) * 6144 + bof2);
            hR = MFMA16(hf[ks], bf0, hR);
            hZ = MFMA16(hf[ks], bf1, hZ);
            hN = MFMA16(hf[ks], bf2, hN);
        }

        // ---- epilogue: gating; C/D layout col=lane&15, row=qg*4+r ----
        unsigned short hbf[4];
#pragma unroll
        for (int r = 0; r < 4; ++r) {
            int brow = b0 + wm * 16 + qg * 4 + r;
            float pr = aR[r] + hR[r];
            float pz = aZ[r] + hZ[r];
            float rr = 1.f / (1.f + __expf(-pr));
            float zz = 1.f / (1.f + __expf(-pz));
            float pn = aN[r] + rr * hN[r];
            float ax = fabsf(pn);
            float e2 = __expf(2.f * ax);
            float nn = copysignf(1.f - 2.f / (e2 + 1.f), pn);
            float hprev = bf2f((unsigned short)((j & 1) ? (hw[r] >> 16) : (hw[r] & 0xffff)));
            float hnew = (1.f - zz) * nn + zz * hprev;
            hbf[r] = f2bf(hnew);
            unsigned v = hbf[r];
            unsigned o = __shfl_xor(v, 1);
            if (!(lane & 1))
                st_dev((unsigned*)hout + brow * (H_DIM / 2) + (j >> 1), v | (o << 16));
        }

        // ---- publish (round-3 proven): drain, block barrier, tid0 RMW ----
        asm volatile("s_waitcnt vmcnt(0)" ::: "memory");
        __syncthreads();
        if (tid == 0) {
            __hip_atomic_fetch_add(&flags[bt * NWS + step], 1u,
                                   __ATOMIC_RELAXED, __HIP_MEMORY_SCOPE_AGENT);
        }

        // ---- hseq stores off the critical path ----
        if (step >= SEQ0) {
#pragma unroll
            for (int r = 0; r < 4; ++r) {
                int brow = b0 + wm * 16 + qg * 4 + r;
                unsigned v = hbf[r];
                unsigned o = __shfl_xor(v, 1);
                if (!(lane & 1))
                    *(unsigned*)(hseq + ((size_t)brow * PRE + (step - SEQ0)) * H_DIM +
                                 (j & ~1)) = v | (o << 16);
            }
        }
    };

    for (int step = 0; step < NWS; step += 2) {
        STEP(step, yf0, yf1);
        STEP(step + 1, yf1, yf0);
    }
}

// ---------------------------------------------------------------------------
// fc2 as bf16 MFMA GEMM: out[12288,256] = hseq[12288,512] * w2[256,512]^T + b
// ---------------------------------------------------------------------------
__global__ void __launch_bounds__(256)
fc2_mfma(const unsigned short* __restrict__ hseq,
         const unsigned short* __restrict__ w2,
         const float* __restrict__ bias,
         float* __restrict__ out) {
    const int tid = threadIdx.x;
    const int lane = tid & 63;
    const int w = tid >> 6;
    const int wm = w & 1, wn = w >> 1;
    const int row16 = lane & 15, qg = lane >> 4;
    const int mbase = blockIdx.x * 64 + wm * 32;
    const int nbase = blockIdx.y * 64 + wn * 32;

    f32x4 acc00 = {0.f, 0.f, 0.f, 0.f}, acc01 = {0.f, 0.f, 0.f, 0.f};
    f32x4 acc10 = {0.f, 0.f, 0.f, 0.f}, acc11 = {0.f, 0.f, 0.f, 0.f};

    const unsigned short* ap0 = hseq + (size_t)(mbase + row16) * H_DIM + qg * 8;
    const unsigned short* ap1 = hseq + (size_t)(mbase + 16 + row16) * H_DIM + qg * 8;
    const unsigned short* bp0 = w2 + (size_t)(nbase + row16) * H_DIM + qg * 8;
    const unsigned short* bp1 = w2 + (size_t)(nbase + 16 + row16) * H_DIM + qg * 8;
#pragma unroll
    for (int ks = 0; ks < 16; ++ks) {
        short8 a0 = *(const short8*)(ap0 + ks * 32);
        short8 a1 = *(const short8*)(ap1 + ks * 32);
        short8 b0 = *(const short8*)(bp0 + ks * 32);
        short8 b1 = *(const short8*)(bp1 + ks * 32);
        acc00 = MFMA16(a0, b0, acc00);
        acc01 = MFMA16(a0, b1, acc01);
        acc10 = MFMA16(a1, b0, acc10);
        acc11 = MFMA16(a1, b1, acc11);
    }

#pragma unroll
    for (int r = 0; r < 4; ++r) {
        int r0 = mbase + qg * 4 + r;
        int r1 = r0 + 16;
        int c0 = nbase + row16;
        int c1 = c0 + 16;
        out[(size_t)r0 * I_DIM + c0] = acc00[r] + bias[c0];
        out[(size_t)r0 * I_DIM + c1] = acc01[r] + bias[c1];
        out[(size_t)r1 * I_DIM + c0] = acc10[r] + bias[c0];
        out[(size_t)r1 * I_DIM + c1] = acc11[r] + bias[c1];
    }
}

__global__ void cvt_w2(const float* __restrict__ w, unsigned short* __restrict__ o, int n) {
    int i = blockIdx.x * 256 + threadIdx.x;
    if (i < n) o[i] = f2bf(w[i]);
}

extern "C" void kernel_launch(void* const* d_in, const int* in_sizes, int n_in,
                              void* d_out, int out_size, void* d_ws, size_t ws_size,
                              hipStream_t stream) {
    const float* x     = (const float*)d_in[0];
    const float* fc1_w = (const float*)d_in[1];
    const float* fc1_b = (const float*)d_in[2];
    const float* W_ih  = (const float*)d_in[3];
    const float* W_hh  = (const float*)d_in[4];
    const float* b_ih  = (const float*)d_in[5];
    const float* b_hh  = (const float*)d_in[6];
    const float* fc2_w = (const float*)d_in[7];
    const float* fc2_b = (const float*)d_in[8];
    float* out = (float*)d_out;

    unsigned short* ws = (unsigned short*)d_ws;
    unsigned short* y_bf  = ws;                       // 8388608 us
    unsigned short* h0    = ws + 8388608;             // 262144
    unsigned short* h1    = ws + 8650752;             // 262144
    unsigned short* hseq  = ws + 8912896;             // 6291456
    unsigned short* w2_bf = ws + 15204352;            // 131072
    unsigned* flags = (unsigned*)(ws + 15335424);     // 16*64 u32

    hipMemsetAsync(h0, 0, 262144 * sizeof(unsigned short), stream);
    hipMemsetAsync(flags, 0, 16 * NWS * sizeof(unsigned), stream);

    cvt_w2<<<dim3((I_DIM * H_DIM + 255) / 256), dim3(256), 0, stream>>>(
        fc2_w, w2_bf, I_DIM * H_DIM);

    fc1_kernel<<<dim3(NWS / 8, B_DIM), dim3(256), 0, stream>>>(x, fc1_w, fc1_b, y_bf);

    hipFuncSetAttribute((const void*)gru_persist,
                        hipFuncAttributeMaxDynamicSharedMemorySize, LDSB);

    void* args[] = {(void*)&y_bf, (void*)&W_ih, (void*)&b_ih, (void*)&W_hh,
                    (void*)&b_hh, (void*)&h0, (void*)&h1, (void*)&hseq,
                    (void*)&flags};
    hipLaunchCooperativeKernel((const void*)gru_persist, dim3(256), dim3(256),
                               args, LDSB, stream);

    fc2_mfma<<<dim3((B_DIM * PRE) / 64, I_DIM / 64), dim3(256), 0, stream>>>(
        hseq, w2_bf, fc2_b, out);
}

// Round 12
// 587.557 us; speedup vs baseline: 8.7367x; 1.0028x over previous
//
#include <hip/hip_runtime.h>
#include <math.h>

#define B_DIM 512
#define WS_DIM 128
#define I_DIM 256
#define H_DIM 512
#define NWS 64
#define PRE 24
#define SEQ0 (NWS - PRE)  // 40

typedef __attribute__((ext_vector_type(8))) short short8;
typedef __attribute__((ext_vector_type(4))) float f32x4;

#define MFMA16(a, b, c) __builtin_amdgcn_mfma_f32_16x16x32_bf16((a), (b), (c), 0, 0, 0)

__device__ __forceinline__ unsigned short f2bf(float f) {
    unsigned u = __float_as_uint(f);
    u += 0x7FFF + ((u >> 16) & 1);
    return (unsigned short)(u >> 16);
}
__device__ __forceinline__ float bf2f(unsigned short h) {
    return __uint_as_float(((unsigned)h) << 16);
}

// Device-coherent (MALL) accesses: bypass the non-coherent per-XCD L2s.
__device__ __forceinline__ unsigned ld_dev(const unsigned* p) {
    return __hip_atomic_load((unsigned*)p, __ATOMIC_RELAXED, __HIP_MEMORY_SCOPE_AGENT);
}
__device__ __forceinline__ unsigned long long ld_dev64(const unsigned long long* p) {
    return __hip_atomic_load((unsigned long long*)p, __ATOMIC_RELAXED, __HIP_MEMORY_SCOPE_AGENT);
}
__device__ __forceinline__ void st_dev(unsigned* p, unsigned v) {
    __hip_atomic_store(p, v, __ATOMIC_RELAXED, __HIP_MEMORY_SCOPE_AGENT);
}

// ---------------------------------------------------------------------------
// K1: fc1 over the time axis -> y bf16.
// NEW: 32 n-rows per block (grid 2 x B). acc in VGPRs; fc1_w read at wave-
// uniform addresses (scalarizes to s_load + v_fmac with SGPR operand).
// Same fp32 summation order as the proven round-3 fc1 -> bitwise-same y.
// x traffic: 2 reads of x total (was 8).
// ---------------------------------------------------------------------------
__global__ void __launch_bounds__(256) fc1_kernel(const float* __restrict__ x,
                                                  const float* __restrict__ fc1_w,
                                                  const float* __restrict__ fc1_b,
                                                  unsigned short* __restrict__ y) {
    const int b = blockIdx.y;
    const int n0 = blockIdx.x * 32;  // 0 or 32
    const int i = threadIdx.x;       // 0..255 == I_DIM

    float acc[32];
#pragma unroll
    for (int n = 0; n < 32; ++n) acc[n] = fc1_b[n0 + n];

    const float* xb = x + (size_t)b * WS_DIM * I_DIM + i;
    const float* wb = fc1_w + (size_t)n0 * WS_DIM;
    for (int t = 0; t < WS_DIM; ++t) {
        float xv = xb[(size_t)t * I_DIM];
#pragma unroll
        for (int n = 0; n < 32; ++n) acc[n] += xv * wb[n * WS_DIM + t];
    }

    unsigned short* yb = y + ((size_t)b * NWS + n0) * I_DIM + i;
#pragma unroll
    for (int n = 0; n < 32; ++n) yb[(size_t)n * I_DIM] = f2bf(acc[n]);
}

// ---------------------------------------------------------------------------
// Persistent GRU recurrence — BYTE-IDENTICAL to the round-8 PASSING kernel.
// (Sync protocol frozen: 2/2 passes for this exact shape, 7/7 failures for
// every deviation — do not modify without an in-kernel diagnostic channel.)
// ---------------------------------------------------------------------------
#define LDSB (24 * 96 * 64)  // 147456 bytes

__global__ void __launch_bounds__(256, 1)
gru_persist(const unsigned short* __restrict__ y,  // [B,NWS,I] bf16
            const float* __restrict__ Wih, const float* __restrict__ bih,
            const float* __restrict__ Whh, const float* __restrict__ bhh,
            unsigned short* __restrict__ hA,   // ping [B,H] bf16 (pre-zeroed)
            unsigned short* __restrict__ hB,   // pong
            unsigned short* __restrict__ hseq, // [B,PRE,H] bf16
            unsigned* __restrict__ flags) {    // [16][NWS] (pre-zeroed)
    extern __shared__ char lds[];
    const int tid = threadIdx.x;
    const int lane = tid & 63;
    const int w = tid >> 6;
    const int wm = w & 1;
    const int jh = w >> 1;
    const int bt = blockIdx.x & 15;
    const int jt = blockIdx.x >> 4;
    const int b0 = bt * 32;
    const int j0 = jt * 32;

    // ---- one-time weight preload into swizzled LDS (round-3 verbatim) ----
    for (int idx = tid; idx < 96 * 768; idx += 256) {
        int n = idx / 768, k = idx % 768;
        int g = n >> 5, jj = n & 31;
        int srow = g * H_DIM + j0 + jj;
        float wv = (k < I_DIM) ? Wih[(size_t)srow * I_DIM + k]
                               : Whh[(size_t)srow * H_DIM + (k - I_DIM)];
        int ks = k >> 5, q = (k & 31) >> 3, e = k & 7;
        int byteoff = ks * 6144 + (((n * 64 + q * 16) ^ ((n & 7) << 4)) + e * 2);
        *(unsigned short*)(lds + byteoff) = f2bf(wv);
    }

    const int row16 = lane & 15;
    const int qg = lane >> 4;
    const int bbA = b0 + wm * 16 + row16;  // A-fragment source row
    const int jj = jh * 16 + row16;        // C col within 32-j slice
    const int j = j0 + jj;

    const int n0r = jj, n1r = 32 + jj, n2r = 64 + jj;
    const int bof0 = (n0r * 64 + qg * 16) ^ ((n0r & 7) << 4);
    const int bof1 = (n1r * 64 + qg * 16) ^ ((n1r & 7) << 4);
    const int bof2 = (n2r * 64 + qg * 16) ^ ((n2r & 7) << 4);

    const float br_i = bih[j], br_h = bhh[j];
    const float bz_i = bih[H_DIM + j], bz_h = bhh[H_DIM + j];
    const float bn_i = bih[2 * H_DIM + j], bn_h = bhh[2 * H_DIM + j];

    __syncthreads();  // LDS weights ready (one-time)

    const unsigned short* ybase = y + (size_t)bbA * NWS * I_DIM + qg * 8;

    short8 yf0[8], yf1[8];
#pragma unroll
    for (int ks = 0; ks < 8; ++ks) yf0[ks] = *(const short8*)(ybase + ks * 32);

    auto STEP = [&](int step, short8(&yc)[8], short8(&yn)[8]) {
        const unsigned short* hin = (step & 1) ? hB : hA;
        unsigned short* hout      = (step & 1) ? hA : hB;

        f32x4 aR = {br_i, br_i, br_i, br_i};
        f32x4 aZ = {bz_i, bz_i, bz_i, bz_i};
        f32x4 aN = {bn_i, bn_i, bn_i, bn_i};

        // ---- input phase (no h dependency) ----
#pragma unroll
        for (int ks = 0; ks < 8; ++ks) {
            short8 bf0 = *(const short8*)(lds + ks * 6144 + bof0);
            short8 bf1 = *(const short8*)(lds + ks * 6144 + bof1);
            short8 bf2 = *(const short8*)(lds + ks * 6144 + bof2);
            aR = MFMA16(yc[ks], bf0, aR);
            aZ = MFMA16(yc[ks], bf1, aZ);
            aN = MFMA16(yc[ks], bf2, aN);
        }

        // ---- prefetch next step's y fragments (overlaps the wait) ----
        int sn = (step + 1 < NWS) ? step + 1 : NWS - 1;
        const unsigned short* ypn = ybase + (size_t)sn * I_DIM;
#pragma unroll
        for (int ks = 0; ks < 8; ++ks) yn[ks] = *(const short8*)(ypn + ks * 32);

        // ---- wait (round-3 proven): tid0 spins on block counter, barrier ----
        if (step > 0) {
            if (tid == 0) {
                unsigned* f = &flags[bt * NWS + (step - 1)];
                while (__hip_atomic_load(f, __ATOMIC_RELAXED,
                                         __HIP_MEMORY_SCOPE_AGENT) < 16u)
                    __builtin_amdgcn_s_sleep(1);
            }
            __syncthreads();
        }

        // ---- h fragment loads (MALL-coherent) ----
        const unsigned long long* hq = (const unsigned long long*)(hin + (size_t)bbA * H_DIM);
        short8 hf[16];
#pragma unroll
        for (int ks = 0; ks < 16; ++ks) {
            union { unsigned long long u[2]; short8 s; } t;
            t.u[0] = ld_dev64(hq + ks * 8 + qg * 2);
            t.u[1] = ld_dev64(hq + ks * 8 + qg * 2 + 1);
            hf[ks] = t.s;
        }
        // hprev for the epilogue (overlaps MFMA below)
        unsigned hw[4];
        const unsigned* h32 = (const unsigned*)hin;
#pragma unroll
        for (int r = 0; r < 4; ++r) {
            int brow = b0 + wm * 16 + qg * 4 + r;
            hw[r] = ld_dev(h32 + brow * (H_DIM / 2) + (j >> 1));
        }

        // ---- hidden phase: B-operands from LDS ----
        f32x4 hR = {br_h, br_h, br_h, br_h};
        f32x4 hZ = {bz_h, bz_h, bz_h, bz_h};
        f32x4 hN = {bn_h, bn_h, bn_h, bn_h};
#pragma unroll
        for (int ks = 0; ks < 16; ++ks) {
            short8 bf0 = *(const short8*)(lds + (8 + ks) * 6144 + bof0);
            short8 bf1 = *(const short8*)(lds + (8 + ks) * 6144 + bof1);
            short8 bf2 = *(const short8*)(lds + (8 + ks) * 6144 + bof2);
            hR = MFMA16(hf[ks], bf0, hR);
            hZ = MFMA16(hf[ks], bf1, hZ);
            hN = MFMA16(hf[ks], bf2, hN);
        }

        // ---- epilogue: gating; C/D layout col=lane&15, row=qg*4+r ----
        unsigned short hbf[4];
#pragma unroll
        for (int r = 0; r < 4; ++r) {
            int brow = b0 + wm * 16 + qg * 4 + r;
            float pr = aR[r] + hR[r];
            float pz = aZ[r] + hZ[r];
            float rr = 1.f / (1.f + __expf(-pr));
            float zz = 1.f / (1.f + __expf(-pz));
            float pn = aN[r] + rr * hN[r];
            float ax = fabsf(pn);
            float e2 = __expf(2.f * ax);
            float nn = copysignf(1.f - 2.f / (e2 + 1.f), pn);
            float hprev = bf2f((unsigned short)((j & 1) ? (hw[r] >> 16) : (hw[r] & 0xffff)));
            float hnew = (1.f - zz) * nn + zz * hprev;
            hbf[r] = f2bf(hnew);
            unsigned v = hbf[r];
            unsigned o = __shfl_xor(v, 1);
            if (!(lane & 1))
                st_dev((unsigned*)hout + brow * (H_DIM / 2) + (j >> 1), v | (o << 16));
        }

        // ---- publish (round-3 proven): drain, block barrier, tid0 RMW ----
        asm volatile("s_waitcnt vmcnt(0)" ::: "memory");
        __syncthreads();
        if (tid == 0) {
            __hip_atomic_fetch_add(&flags[bt * NWS + step], 1u,
                                   __ATOMIC_RELAXED, __HIP_MEMORY_SCOPE_AGENT);
        }

        // ---- hseq stores off the critical path ----
        if (step >= SEQ0) {
#pragma unroll
            for (int r = 0; r < 4; ++r) {
                int brow = b0 + wm * 16 + qg * 4 + r;
                unsigned v = hbf[r];
                unsigned o = __shfl_xor(v, 1);
                if (!(lane & 1))
                    *(unsigned*)(hseq + ((size_t)brow * PRE + (step - SEQ0)) * H_DIM +
                                 (j & ~1)) = v | (o << 16);
            }
        }
    };

    for (int step = 0; step < NWS; step += 2) {
        STEP(step, yf0, yf1);
        STEP(step + 1, yf1, yf0);
    }
}

// ---------------------------------------------------------------------------
// fc2 as bf16 MFMA GEMM: out[12288,256] = hseq[12288,512] * w2[256,512]^T + b
// ---------------------------------------------------------------------------
__global__ void __launch_bounds__(256)
fc2_mfma(const unsigned short* __restrict__ hseq,
         const unsigned short* __restrict__ w2,
         const float* __restrict__ bias,
         float* __restrict__ out) {
    const int tid = threadIdx.x;
    const int lane = tid & 63;
    const int w = tid >> 6;
    const int wm = w & 1, wn = w >> 1;
    const int row16 = lane & 15, qg = lane >> 4;
    const int mbase = blockIdx.x * 64 + wm * 32;
    const int nbase = blockIdx.y * 64 + wn * 32;

    f32x4 acc00 = {0.f, 0.f, 0.f, 0.f}, acc01 = {0.f, 0.f, 0.f, 0.f};
    f32x4 acc10 = {0.f, 0.f, 0.f, 0.f}, acc11 = {0.f, 0.f, 0.f, 0.f};

    const unsigned short* ap0 = hseq + (size_t)(mbase + row16) * H_DIM + qg * 8;
    const unsigned short* ap1 = hseq + (size_t)(mbase + 16 + row16) * H_DIM + qg * 8;
    const unsigned short* bp0 = w2 + (size_t)(nbase + row16) * H_DIM + qg * 8;
    const unsigned short* bp1 = w2 + (size_t)(nbase + 16 + row16) * H_DIM + qg * 8;
#pragma unroll
    for (int ks = 0; ks < 16; ++ks) {
        short8 a0 = *(const short8*)(ap0 + ks * 32);
        short8 a1 = *(const short8*)(ap1 + ks * 32);
        short8 b0 = *(const short8*)(bp0 + ks * 32);
        short8 b1 = *(const short8*)(bp1 + ks * 32);
        acc00 = MFMA16(a0, b0, acc00);
        acc01 = MFMA16(a0, b1, acc01);
        acc10 = MFMA16(a1, b0, acc10);
        acc11 = MFMA16(a1, b1, acc11);
    }

#pragma unroll
    for (int r = 0; r < 4; ++r) {
        int r0 = mbase + qg * 4 + r;
        int r1 = r0 + 16;
        int c0 = nbase + row16;
        int c1 = c0 + 16;
        out[(size_t)r0 * I_DIM + c0] = acc00[r] + bias[c0];
        out[(size_t)r0 * I_DIM + c1] = acc01[r] + bias[c1];
        out[(size_t)r1 * I_DIM + c0] = acc10[r] + bias[c0];
        out[(size_t)r1 * I_DIM + c1] = acc11[r] + bias[c1];
    }
}

__global__ void cvt_w2(const float* __restrict__ w, unsigned short* __restrict__ o, int n) {
    int i = blockIdx.x * 256 + threadIdx.x;
    if (i < n) o[i] = f2bf(w[i]);
}

extern "C" void kernel_launch(void* const* d_in, const int* in_sizes, int n_in,
                              void* d_out, int out_size, void* d_ws, size_t ws_size,
                              hipStream_t stream) {
    const float* x     = (const float*)d_in[0];
    const float* fc1_w = (const float*)d_in[1];
    const float* fc1_b = (const float*)d_in[2];
    const float* W_ih  = (const float*)d_in[3];
    const float* W_hh  = (const float*)d_in[4];
    const float* b_ih  = (const float*)d_in[5];
    const float* b_hh  = (const float*)d_in[6];
    const float* fc2_w = (const float*)d_in[7];
    const float* fc2_b = (const float*)d_in[8];
    float* out = (float*)d_out;

    unsigned short* ws = (unsigned short*)d_ws;
    unsigned short* y_bf  = ws;                       // 8388608 us
    unsigned short* h0    = ws + 8388608;             // 262144
    unsigned short* h1    = ws + 8650752;             // 262144
    unsigned short* hseq  = ws + 8912896;             // 6291456
    unsigned short* w2_bf = ws + 15204352;            // 131072
    unsigned* flags = (unsigned*)(ws + 15335424);     // 16*64 u32

    hipMemsetAsync(h0, 0, 262144 * sizeof(unsigned short), stream);
    hipMemsetAsync(flags, 0, 16 * NWS * sizeof(unsigned), stream);

    cvt_w2<<<dim3((I_DIM * H_DIM + 255) / 256), dim3(256), 0, stream>>>(
        fc2_w, w2_bf, I_DIM * H_DIM);

    fc1_kernel<<<dim3(2, B_DIM), dim3(256), 0, stream>>>(x, fc1_w, fc1_b, y_bf);

    hipFuncSetAttribute((const void*)gru_persist,
                        hipFuncAttributeMaxDynamicSharedMemorySize, LDSB);

    void* args[] = {(void*)&y_bf, (void*)&W_ih, (void*)&b_ih, (void*)&W_hh,
                    (void*)&b_hh, (void*)&h0, (void*)&h1, (void*)&hseq,
                    (void*)&flags};
    hipLaunchCooperativeKernel((const void*)gru_persist, dim3(256), dim3(256),
                               args, LDSB, stream);

    fc2_mfma<<<dim3((B_DIM * PRE) / 64, I_DIM / 64), dim3(256), 0, stream>>>(
        hseq, w2_bf, fc2_b, out);
}

// Round 13
// 585.742 us; speedup vs baseline: 8.7638x; 1.0031x over previous
//
#include <hip/hip_runtime.h>
#include <math.h>

#define B_DIM 512
#define WS_DIM 128
#define I_DIM 256
#define H_DIM 512
#define NWS 64
#define PRE 24
#define SEQ0 (NWS - PRE)  // 40

typedef __attribute__((ext_vector_type(8))) short short8;
typedef __attribute__((ext_vector_type(4))) float f32x4;

#define MFMA16(a, b, c) __builtin_amdgcn_mfma_f32_16x16x32_bf16((a), (b), (c), 0, 0, 0)

__device__ __forceinline__ unsigned short f2bf(float f) {
    unsigned u = __float_as_uint(f);
    u += 0x7FFF + ((u >> 16) & 1);
    return (unsigned short)(u >> 16);
}
__device__ __forceinline__ float bf2f(unsigned short h) {
    return __uint_as_float(((unsigned)h) << 16);
}

// Device-coherent (MALL) accesses: bypass the non-coherent per-XCD L2s.
__device__ __forceinline__ unsigned ld_dev(const unsigned* p) {
    return __hip_atomic_load((unsigned*)p, __ATOMIC_RELAXED, __HIP_MEMORY_SCOPE_AGENT);
}
__device__ __forceinline__ unsigned long long ld_dev64(const unsigned long long* p) {
    return __hip_atomic_load((unsigned long long*)p, __ATOMIC_RELAXED, __HIP_MEMORY_SCOPE_AGENT);
}
__device__ __forceinline__ void st_dev(unsigned* p, unsigned v) {
    __hip_atomic_store(p, v, __ATOMIC_RELAXED, __HIP_MEMORY_SCOPE_AGENT);
}

// ---------------------------------------------------------------------------
// K1: fc1 over the time axis -> y bf16.
// One block per b: full fc1_w (64x128 f32 = 32KB) in LDS (broadcast reads,
// proven round-3 pattern), x read ONCE. Same per-n summation order as the
// proven fc1 -> bitwise-identical y.
// ---------------------------------------------------------------------------
__global__ void __launch_bounds__(256) fc1_kernel(const float* __restrict__ x,
                                                  const float* __restrict__ fc1_w,
                                                  const float* __restrict__ fc1_b,
                                                  unsigned short* __restrict__ y) {
    __shared__ float wsm[NWS * WS_DIM];  // 64*128 f32 = 32KB
    const int b = blockIdx.x;
    const int i = threadIdx.x;  // 0..255 == I_DIM

    for (int idx = i; idx < NWS * WS_DIM; idx += 256) wsm[idx] = fc1_w[idx];
    __syncthreads();

    float acc[NWS];
#pragma unroll
    for (int n = 0; n < NWS; ++n) acc[n] = fc1_b[n];

    const float* xb = x + (size_t)b * WS_DIM * I_DIM + i;
    for (int t = 0; t < WS_DIM; ++t) {
        float xv = xb[(size_t)t * I_DIM];
#pragma unroll
        for (int n = 0; n < NWS; ++n) acc[n] += xv * wsm[n * WS_DIM + t];
    }

    unsigned short* yb = y + (size_t)b * NWS * I_DIM + i;
#pragma unroll
    for (int n = 0; n < NWS; ++n) yb[(size_t)n * I_DIM] = f2bf(acc[n]);
}

// ---------------------------------------------------------------------------
// Persistent GRU recurrence — BYTE-IDENTICAL to the round-8/12 PASSING kernel.
// (Sync protocol frozen: 3/3 passes for this exact shape, 7/7 failures for
// every deviation — do not modify.)
// ---------------------------------------------------------------------------
#define LDSB (24 * 96 * 64)  // 147456 bytes

__global__ void __launch_bounds__(256, 1)
gru_persist(const unsigned short* __restrict__ y,  // [B,NWS,I] bf16
            const float* __restrict__ Wih, const float* __restrict__ bih,
            const float* __restrict__ Whh, const float* __restrict__ bhh,
            unsigned short* __restrict__ hA,   // ping [B,H] bf16 (pre-zeroed)
            unsigned short* __restrict__ hB,   // pong
            unsigned short* __restrict__ hseq, // [B,PRE,H] bf16
            unsigned* __restrict__ flags) {    // [16][NWS] (pre-zeroed)
    extern __shared__ char lds[];
    const int tid = threadIdx.x;
    const int lane = tid & 63;
    const int w = tid >> 6;
    const int wm = w & 1;
    const int jh = w >> 1;
    const int bt = blockIdx.x & 15;
    const int jt = blockIdx.x >> 4;
    const int b0 = bt * 32;
    const int j0 = jt * 32;

    // ---- one-time weight preload into swizzled LDS (round-3 verbatim) ----
    for (int idx = tid; idx < 96 * 768; idx += 256) {
        int n = idx / 768, k = idx % 768;
        int g = n >> 5, jj = n & 31;
        int srow = g * H_DIM + j0 + jj;
        float wv = (k < I_DIM) ? Wih[(size_t)srow * I_DIM + k]
                               : Whh[(size_t)srow * H_DIM + (k - I_DIM)];
        int ks = k >> 5, q = (k & 31) >> 3, e = k & 7;
        int byteoff = ks * 6144 + (((n * 64 + q * 16) ^ ((n & 7) << 4)) + e * 2);
        *(unsigned short*)(lds + byteoff) = f2bf(wv);
    }

    const int row16 = lane & 15;
    const int qg = lane >> 4;
    const int bbA = b0 + wm * 16 + row16;  // A-fragment source row
    const int jj = jh * 16 + row16;        // C col within 32-j slice
    const int j = j0 + jj;

    const int n0r = jj, n1r = 32 + jj, n2r = 64 + jj;
    const int bof0 = (n0r * 64 + qg * 16) ^ ((n0r & 7) << 4);
    const int bof1 = (n1r * 64 + qg * 16) ^ ((n1r & 7) << 4);
    const int bof2 = (n2r * 64 + qg * 16) ^ ((n2r & 7) << 4);

    const float br_i = bih[j], br_h = bhh[j];
    const float bz_i = bih[H_DIM + j], bz_h = bhh[H_DIM + j];
    const float bn_i = bih[2 * H_DIM + j], bn_h = bhh[2 * H_DIM + j];

    __syncthreads();  // LDS weights ready (one-time)

    const unsigned short* ybase = y + (size_t)bbA * NWS * I_DIM + qg * 8;

    short8 yf0[8], yf1[8];
#pragma unroll
    for (int ks = 0; ks < 8; ++ks) yf0[ks] = *(const short8*)(ybase + ks * 32);

    auto STEP = [&](int step, short8(&yc)[8], short8(&yn)[8]) {
        const unsigned short* hin = (step & 1) ? hB : hA;
        unsigned short* hout      = (step & 1) ? hA : hB;

        f32x4 aR = {br_i, br_i, br_i, br_i};
        f32x4 aZ = {bz_i, bz_i, bz_i, bz_i};
        f32x4 aN = {bn_i, bn_i, bn_i, bn_i};

        // ---- input phase (no h dependency) ----
#pragma unroll
        for (int ks = 0; ks < 8; ++ks) {
            short8 bf0 = *(const short8*)(lds + ks * 6144 + bof0);
            short8 bf1 = *(const short8*)(lds + ks * 6144 + bof1);
            short8 bf2 = *(const short8*)(lds + ks * 6144 + bof2);
            aR = MFMA16(yc[ks], bf0, aR);
            aZ = MFMA16(yc[ks], bf1, aZ);
            aN = MFMA16(yc[ks], bf2, aN);
        }

        // ---- prefetch next step's y fragments (overlaps the wait) ----
        int sn = (step + 1 < NWS) ? step + 1 : NWS - 1;
        const unsigned short* ypn = ybase + (size_t)sn * I_DIM;
#pragma unroll
        for (int ks = 0; ks < 8; ++ks) yn[ks] = *(const short8*)(ypn + ks * 32);

        // ---- wait (round-3 proven): tid0 spins on block counter, barrier ----
        if (step > 0) {
            if (tid == 0) {
                unsigned* f = &flags[bt * NWS + (step - 1)];
                while (__hip_atomic_load(f, __ATOMIC_RELAXED,
                                         __HIP_MEMORY_SCOPE_AGENT) < 16u)
                    __builtin_amdgcn_s_sleep(1);
            }
            __syncthreads();
        }

        // ---- h fragment loads (MALL-coherent) ----
        const unsigned long long* hq = (const unsigned long long*)(hin + (size_t)bbA * H_DIM);
        short8 hf[16];
#pragma unroll
        for (int ks = 0; ks < 16; ++ks) {
            union { unsigned long long u[2]; short8 s; } t;
            t.u[0] = ld_dev64(hq + ks * 8 + qg * 2);
            t.u[1] = ld_dev64(hq + ks * 8 + qg * 2 + 1);
            hf[ks] = t.s;
        }
        // hprev for the epilogue (overlaps MFMA below)
        unsigned hw[4];
        const unsigned* h32 = (const unsigned*)hin;
#pragma unroll
        for (int r = 0; r < 4; ++r) {
            int brow = b0 + wm * 16 + qg * 4 + r;
            hw[r] = ld_dev(h32 + brow * (H_DIM / 2) + (j >> 1));
        }

        // ---- hidden phase: B-operands from LDS ----
        f32x4 hR = {br_h, br_h, br_h, br_h};
        f32x4 hZ = {bz_h, bz_h, bz_h, bz_h};
        f32x4 hN = {bn_h, bn_h, bn_h, bn_h};
#pragma unroll
        for (int ks = 0; ks < 16; ++ks) {
            short8 bf0 = *(const short8*)(lds + (8 + ks) * 6144 + bof0);
            short8 bf1 = *(const short8*)(lds + (8 + ks) * 6144 + bof1);
            short8 bf2 = *(const short8*)(lds + (8 + ks) * 6144 + bof2);
            hR = MFMA16(hf[ks], bf0, hR);
            hZ = MFMA16(hf[ks], bf1, hZ);
            hN = MFMA16(hf[ks], bf2, hN);
        }

        // ---- epilogue: gating; C/D layout col=lane&15, row=qg*4+r ----
        unsigned short hbf[4];
#pragma unroll
        for (int r = 0; r < 4; ++r) {
            int brow = b0 + wm * 16 + qg * 4 + r;
            float pr = aR[r] + hR[r];
            float pz = aZ[r] + hZ[r];
            float rr = 1.f / (1.f + __expf(-pr));
            float zz = 1.f / (1.f + __expf(-pz));
            float pn = aN[r] + rr * hN[r];
            float ax = fabsf(pn);
            float e2 = __expf(2.f * ax);
            float nn = copysignf(1.f - 2.f / (e2 + 1.f), pn);
            float hprev = bf2f((unsigned short)((j & 1) ? (hw[r] >> 16) : (hw[r] & 0xffff)));
            float hnew = (1.f - zz) * nn + zz * hprev;
            hbf[r] = f2bf(hnew);
            unsigned v = hbf[r];
            unsigned o = __shfl_xor(v, 1);
            if (!(lane & 1))
                st_dev((unsigned*)hout + brow * (H_DIM / 2) + (j >> 1), v | (o << 16));
        }

        // ---- publish (round-3 proven): drain, block barrier, tid0 RMW ----
        asm volatile("s_waitcnt vmcnt(0)" ::: "memory");
        __syncthreads();
        if (tid == 0) {
            __hip_atomic_fetch_add(&flags[bt * NWS + step], 1u,
                                   __ATOMIC_RELAXED, __HIP_MEMORY_SCOPE_AGENT);
        }

        // ---- hseq stores off the critical path ----
        if (step >= SEQ0) {
#pragma unroll
            for (int r = 0; r < 4; ++r) {
                int brow = b0 + wm * 16 + qg * 4 + r;
                unsigned v = hbf[r];
                unsigned o = __shfl_xor(v, 1);
                if (!(lane & 1))
                    *(unsigned*)(hseq + ((size_t)brow * PRE + (step - SEQ0)) * H_DIM +
                                 (j & ~1)) = v | (o << 16);
            }
        }
    };

    for (int step = 0; step < NWS; step += 2) {
        STEP(step, yf0, yf1);
        STEP(step + 1, yf1, yf0);
    }
}

// ---------------------------------------------------------------------------
// fc2 as bf16 MFMA GEMM: out[12288,256] = hseq[12288,512] * w2[256,512]^T + b
// v2: one block per 64 M-rows covering FULL N=256 -> hseq read once (was 4x).
// Wave w: wm=w&1 -> M 32-half, wn=w>>1 -> N 128-half; per wave 2x8 16x16 tiles.
// ---------------------------------------------------------------------------
__global__ void __launch_bounds__(256)
fc2_mfma(const unsigned short* __restrict__ hseq,
         const unsigned short* __restrict__ w2,
         const float* __restrict__ bias,
         float* __restrict__ out) {
    const int tid = threadIdx.x;
    const int lane = tid & 63;
    const int w = tid >> 6;
    const int wm = w & 1, wn = w >> 1;
    const int row16 = lane & 15, qg = lane >> 4;
    const int mbase = blockIdx.x * 64 + wm * 32;
    const int nbase = wn * 128;

    f32x4 acc[2][8];
#pragma unroll
    for (int mt = 0; mt < 2; ++mt)
#pragma unroll
        for (int nt = 0; nt < 8; ++nt) acc[mt][nt] = f32x4{0.f, 0.f, 0.f, 0.f};

    const unsigned short* ap = hseq + (size_t)(mbase + row16) * H_DIM + qg * 8;
    const unsigned short* bp = w2 + (size_t)(nbase + row16) * H_DIM + qg * 8;
#pragma unroll
    for (int ks = 0; ks < 16; ++ks) {
        short8 a0 = *(const short8*)(ap + ks * 32);
        short8 a1 = *(const short8*)(ap + 16 * H_DIM + ks * 32);
        short8 bfr[8];
#pragma unroll
        for (int nt = 0; nt < 8; ++nt)
            bfr[nt] = *(const short8*)(bp + (size_t)nt * 16 * H_DIM + ks * 32);
#pragma unroll
        for (int nt = 0; nt < 8; ++nt) {
            acc[0][nt] = MFMA16(a0, bfr[nt], acc[0][nt]);
            acc[1][nt] = MFMA16(a1, bfr[nt], acc[1][nt]);
        }
    }

#pragma unroll
    for (int mt = 0; mt < 2; ++mt)
#pragma unroll
        for (int nt = 0; nt < 8; ++nt)
#pragma unroll
            for (int r = 0; r < 4; ++r) {
                int row = mbase + mt * 16 + qg * 4 + r;
                int col = nbase + nt * 16 + row16;
                out[(size_t)row * I_DIM + col] = acc[mt][nt][r] + bias[col];
            }
}

__global__ void cvt_w2(const float* __restrict__ w, unsigned short* __restrict__ o, int n) {
    int i = blockIdx.x * 256 + threadIdx.x;
    if (i < n) o[i] = f2bf(w[i]);
}

extern "C" void kernel_launch(void* const* d_in, const int* in_sizes, int n_in,
                              void* d_out, int out_size, void* d_ws, size_t ws_size,
                              hipStream_t stream) {
    const float* x     = (const float*)d_in[0];
    const float* fc1_w = (const float*)d_in[1];
    const float* fc1_b = (const float*)d_in[2];
    const float* W_ih  = (const float*)d_in[3];
    const float* W_hh  = (const float*)d_in[4];
    const float* b_ih  = (const float*)d_in[5];
    const float* b_hh  = (const float*)d_in[6];
    const float* fc2_w = (const float*)d_in[7];
    const float* fc2_b = (const float*)d_in[8];
    float* out = (float*)d_out;

    unsigned short* ws = (unsigned short*)d_ws;
    unsigned short* y_bf  = ws;                       // 8388608 us
    unsigned short* h0    = ws + 8388608;             // 262144
    unsigned short* h1    = ws + 8650752;             // 262144
    unsigned short* hseq  = ws + 8912896;             // 6291456
    unsigned short* w2_bf = ws + 15204352;            // 131072
    unsigned* flags = (unsigned*)(ws + 15335424);     // 16*64 u32

    hipMemsetAsync(h0, 0, 262144 * sizeof(unsigned short), stream);
    hipMemsetAsync(flags, 0, 16 * NWS * sizeof(unsigned), stream);

    cvt_w2<<<dim3((I_DIM * H_DIM + 255) / 256), dim3(256), 0, stream>>>(
        fc2_w, w2_bf, I_DIM * H_DIM);

    fc1_kernel<<<dim3(B_DIM), dim3(256), 0, stream>>>(x, fc1_w, fc1_b, y_bf);

    hipFuncSetAttribute((const void*)gru_persist,
                        hipFuncAttributeMaxDynamicSharedMemorySize, LDSB);

    void* args[] = {(void*)&y_bf, (void*)&W_ih, (void*)&b_ih, (void*)&W_hh,
                    (void*)&b_hh, (void*)&h0, (void*)&h1, (void*)&hseq,
                    (void*)&flags};
    hipLaunchCooperativeKernel((const void*)gru_persist, dim3(256), dim3(256),
                               args, LDSB, stream);

    fc2_mfma<<<dim3((B_DIM * PRE) / 64), dim3(256), 0, stream>>>(
        hseq, w2_bf, fc2_b, out);
}